// Round 18
// baseline (63.585 us; speedup 1.0000x reference)
//
#include <hip/hip_runtime.h>
#include <hip/hip_bf16.h>

#define NELEM 16384
#define DIN 768
#define DMID 128
#define DOUT 4

typedef __attribute__((ext_vector_type(8))) short short8;
typedef __attribute__((ext_vector_type(4))) float f32x4;
typedef __attribute__((ext_vector_type(2))) unsigned uint32x2;
typedef __attribute__((ext_vector_type(4))) unsigned uint32x4;

__device__ __forceinline__ unsigned f2bf(float f) {
    unsigned u = __float_as_uint(f);
    return (u + 0x7FFFu + ((u >> 16) & 1u)) >> 16;   // RNE bf16
}
__device__ __forceinline__ unsigned wscan_inc(unsigned x, int lane) {
    unsigned inc = x;
#pragma unroll
    for (int off = 1; off < 64; off <<= 1) {
        unsigned y = __shfl_up(inc, off);
        if (lane >= off) inc += y;
    }
    return inc;
}

// threshold barrier; counter zeroed by launch-time 4B memset (proven R9-R12).
__device__ __forceinline__ void gbar(unsigned* cnt, unsigned thresh) {
    __syncthreads();
    if (threadIdx.x == 0) {
        __hip_atomic_fetch_add(cnt, 1u, __ATOMIC_ACQ_REL, __HIP_MEMORY_SCOPE_AGENT);
        while (__hip_atomic_load(cnt, __ATOMIC_RELAXED, __HIP_MEMORY_SCOPE_AGENT) < thresh)
            __builtin_amdgcn_s_sleep(1);
        (void)__hip_atomic_load(cnt, __ATOMIC_ACQUIRE, __HIP_MEMORY_SCOPE_AGENT);
    }
    __syncthreads();
}

// ===========================================================================
// FAST7 ws layout:
//   Gb@0(64K) SD@65536(64K) WtG@131072(192K) stage@327680(128K u64)
//   LCnt@458752(128) RB@458880(512K) CS@983168(16K) bar@999552(64) -> 999,616
// Gb word = vocab<<9 | s ; SD[u] = b<<19 | start<<10 | len
// stage[b*512+g] = (u64)vocab<<32 | SDvalue ; LCnt[b] = #groups in row b
// RB[b*4096+w] = row-b vocab bitmap word w (nt-stored, fully overwritten)
// CS[w] = column popcount over 32 rows at word w (phase-1 cooperative)
// Producer->consumer stores are NON-TEMPORAL (bypass local L2 -> MALL).
// ===========================================================================
#define FAST7_WS 999616

// K1: merged. 64 blocks x 256 threads, 2 internal gbar phases.
__global__ __launch_bounds__(256) void merged_kernel(
    const int* __restrict__ vocab_ids, const float* __restrict__ W1,
    unsigned* __restrict__ Gb, unsigned* __restrict__ SD,
    unsigned short* __restrict__ WtG,
    unsigned long long* __restrict__ stage, unsigned* __restrict__ LCnt,
    unsigned* __restrict__ RB, unsigned* __restrict__ CS,
    unsigned* __restrict__ bar, float* __restrict__ out_ids) {
    __shared__ unsigned lbm[4096];       // 16 KB: phase0 row bitmap / phase2 pre1
    __shared__ unsigned voc[512];
    __shared__ unsigned short gel[512];
    __shared__ unsigned gcnt[512];
    __shared__ unsigned gstart[512];
    __shared__ unsigned part[256];
    __shared__ unsigned colred[256];
    __shared__ unsigned wsumL[4];
    __shared__ unsigned Ush;

    const int t = threadIdx.x;
    const int blk = blockIdx.x;
    const int lane = t & 63;
    const int wv = t >> 6;

    // ================= phase 0 =================
    if (blk >= 32) {
        // W1^T -> bf16. Each thread: 12 consecutive outputs of one column c.
        int base = (blk - 32) * 256 + t;        // 0..8191
        int c = base >> 6;                      // 64 threads per column
        int k0 = (base & 63) * 12;
#pragma unroll
        for (int j = 0; j < 3; ++j) {
            int k = k0 + j * 4;
            uint32x2 pk2;
            pk2.x = f2bf(W1[(k + 0) * DMID + c]) | (f2bf(W1[(k + 1) * DMID + c]) << 16);
            pk2.y = f2bf(W1[(k + 2) * DMID + c]) | (f2bf(W1[(k + 3) * DMID + c]) << 16);
            __builtin_nontemporal_store(pk2, (uint32x2*)(WtG + (size_t)c * DIN + k));
        }
    } else {
        const int b = blk;
        // ---- load row + zero LDS ----
#pragma unroll
        for (int i = 0; i < 16; ++i) lbm[t + 256 * i] = 0;
        gcnt[t] = 0; gcnt[t + 256] = 0;
#pragma unroll
        for (int q = 0; q < 2; ++q) {
            int s = q * 256 + t;
            voc[s] = (unsigned)vocab_ids[b * 512 + s];
        }
        __syncthreads();
#pragma unroll
        for (int q = 0; q < 2; ++q) {
            unsigned v = voc[q * 256 + t];
            atomicOr(&lbm[v >> 5], 1u << (v & 31u));
        }
        __syncthreads();
        // ---- dump row bitmap, linear + coalesced + NT ----
#pragma unroll
        for (int i = 0; i < 4; ++i) {
            int w4 = i * 256 + t;
            uint32x4 x;
            x.x = lbm[w4 * 4 + 0]; x.y = lbm[w4 * 4 + 1];
            x.z = lbm[w4 * 4 + 2]; x.w = lbm[w4 * 4 + 3];
            __builtin_nontemporal_store(x, (uint32x4*)(RB + (size_t)b * 4096 + w4 * 4));
        }
        // ---- local chunk-scan -> part[]; LCnt ----
        {
            unsigned sum = 0;
#pragma unroll
            for (int j = 0; j < 16; ++j) sum += (unsigned)__popc(lbm[t * 16 + j]);
            unsigned inc = wscan_inc(sum, lane);
            if (lane == 63) wsumL[wv] = inc;
            __syncthreads();
            unsigned woff = 0;
            for (int i = 0; i < wv; ++i) woff += wsumL[i];
            part[t] = woff + inc - sum;
            if (t == 255) __builtin_nontemporal_store(woff + inc, LCnt + b);
            __syncthreads();
        }
        // ---- group index per element ----
#pragma unroll
        for (int q = 0; q < 2; ++q) {
            int s = q * 256 + t;
            unsigned v = voc[s];
            unsigned lw = v >> 5, c = lw >> 4;
            unsigned g = part[c];
            for (unsigned j = c * 16; j < lw; ++j) g += (unsigned)__popc(lbm[j]);
            g += (unsigned)__popc(lbm[lw] & ((1u << (v & 31u)) - 1u));
            gel[s] = (unsigned short)g;
            atomicAdd(&gcnt[g], 1u);
        }
        __syncthreads();
        // ---- exclusive scan gcnt -> gstart ----
        {
            unsigned a = gcnt[2 * t], b2 = gcnt[2 * t + 1];
            unsigned pair = a + b2;
            unsigned inc = wscan_inc(pair, lane);
            if (lane == 63) wsumL[wv] = inc;
            __syncthreads();
            unsigned woff = 0;
            for (int i = 0; i < wv; ++i) woff += wsumL[i];
            unsigned excl = woff + inc - pair;
            gstart[2 * t] = excl;
            gstart[2 * t + 1] = excl + a;
        }
        __syncthreads();
        // ---- member index + Gb write + leader staging (NT) ----
#pragma unroll
        for (int q = 0; q < 2; ++q) {
            int s = q * 256 + t;
            unsigned g = gel[s];
            unsigned v = voc[s];
            unsigned m = 0;
            if (gcnt[g] > 1) {
                for (int j = 0; j < s; ++j) if (voc[j] == v) ++m;
            }
            __builtin_nontemporal_store((v << 9) | (unsigned)s,
                                        Gb + b * 512 + gstart[g] + m);
            if (m == 0) {
                unsigned sdval = ((unsigned)b << 19) | (gstart[g] << 10) | gcnt[g];
                __builtin_nontemporal_store(((unsigned long long)v << 32) | sdval,
                                            stage + b * 512 + g);
            }
        }
    }

    gbar(bar, 64);

    // ================= phase 1: cooperative colsum (all 64 blocks) =========
    {
        const int w = blk * 64 + lane;           // this block's word window
        const int r0 = wv * 8;                   // rows r0..r0+8
        unsigned partial = 0;
#pragma unroll
        for (int r = 0; r < 8; ++r)
            partial += (unsigned)__popc(RB[(size_t)(r0 + r) * 4096 + w]);
        colred[t] = partial;
        __syncthreads();
        if (t < 64) {
            unsigned cs = colred[t] + colred[t + 64] + colred[t + 128] + colred[t + 192];
            __builtin_nontemporal_store(cs, CS + blk * 64 + t);
        }
    }

    gbar(bar, 128);

    if (blk >= 32) return;

    // ================= phase 2: rank (blocks 0..31 = row b) ================
    const int b = blk;
    {
        // pre1 build from CS (16 KB coalesced)
        unsigned cs[16];
        const uint32x4* my = (const uint32x4*)CS + t * 4;
#pragma unroll
        for (int q = 0; q < 4; ++q) {
            uint32x4 x = my[q];
            cs[q * 4 + 0] = x.x; cs[q * 4 + 1] = x.y;
            cs[q * 4 + 2] = x.z; cs[q * 4 + 3] = x.w;
        }
        unsigned loc[16];
        unsigned run = 0;
#pragma unroll
        for (int i = 0; i < 16; ++i) { loc[i] = run; run += cs[i]; }
        unsigned inc = wscan_inc(run, lane);
        if (lane == 63) wsumL[wv] = inc;
        __syncthreads();
        unsigned woff = 0;
        for (int i = 0; i < wv; ++i) woff += wsumL[i];
        unsigned excl = woff + inc - run;
#pragma unroll
        for (int i = 0; i < 16; ++i) lbm[t * 16 + i] = excl + loc[i];  // pre1
        if (t == 255) Ush = woff + inc;
        __syncthreads();
    }
    const unsigned U = Ush;
    const unsigned cnt = LCnt[b];
    for (unsigned l = t; l < cnt; l += 256) {
        unsigned long long sv = stage[b * 512 + l];
        unsigned v = (unsigned)(sv >> 32);
        unsigned sdval = (unsigned)sv;
        unsigned w = v >> 5, bit = v & 31u;
        unsigned maskLT = (1u << bit) - 1u;
        unsigned rank = lbm[w];                  // pre1[w]
#pragma unroll 8
        for (int b2 = 0; b2 < 32; ++b2) {
            unsigned word = RB[(size_t)b2 * 4096 + w];
            rank += (unsigned)__popc(word & maskLT);
            if (b2 < b) rank += (word >> bit) & 1u;
        }
        __builtin_nontemporal_store(sdval, SD + rank);
        out_ids[2 * rank + 0] = (float)v;
        out_ids[2 * rank + 1] = (float)b;
    }
    for (int u = (int)U + b * 256 + t; u < NELEM; u += 32 * 256) {
        __builtin_nontemporal_store(0u, SD + u);
        out_ids[2 * u + 0] = 0.0f;
        out_ids[2 * u + 1] = 0.0f;
    }
}

// ===========================================================================
// K2: MFMA fused kernel (proven R10-R16). 1024 blocks x 256 thr, 16 rows.
// ===========================================================================
#define FBM 16
__global__ __launch_bounds__(256) void fused_kernel(
    const unsigned* __restrict__ Gb,
    const unsigned* __restrict__ SD,
    const unsigned short* __restrict__ WtG,
    const float* __restrict__ emb,
    const float* __restrict__ b1,
    const float* __restrict__ enc,
    float* __restrict__ out_enc) {
    __shared__ char smem[20736];

    const int t = threadIdx.x;
    const int u0 = blockIdx.x * FBM;
    const int l = t & 63;
    const int w = t >> 6;

    const int ar = t >> 4;
    const int ak4 = t & 15;
    const unsigned sdw = SD[u0 + ar];
    const int lenA = (int)(sdw & 1023u);
    const unsigned embBase = (sdw >> 19) << 9;
    const unsigned gb0 = embBase + ((sdw >> 10) & 511u);

    f32x4 acc0 = {0.f, 0.f, 0.f, 0.f};
    f32x4 acc1 = {0.f, 0.f, 0.f, 0.f};

    for (int kk = 0; kk < DIN; kk += 64) {
        __syncthreads();
        {
            float s0 = 0.f, s1 = 0.f, s2 = 0.f, s3 = 0.f;
            const float* base = emb + (size_t)(kk + ak4 * 4);
            for (int p = 0; p < lenA; ++p) {
                unsigned idx = embBase + (Gb[gb0 + p] & 511u);
                const float4 e4 = *(const float4*)(base + (size_t)idx * DIN);
                s0 += e4.x; s1 += e4.y; s2 += e4.z; s3 += e4.w;
            }
            uint2 packed;
            packed.x = f2bf(s0) | (f2bf(s1) << 16);
            packed.y = f2bf(s2) | (f2bf(s3) << 16);
            *(uint2*)(smem + ar * 144 + ak4 * 8) = packed;
        }
        {
#pragma unroll
            for (int i = 0; i < 4; ++i) {
                int q = t + i * 256;
                int c = q >> 3;
                int uo = q & 7;
                uint4 dv = *(const uint4*)(WtG + (size_t)c * DIN + kk + uo * 8);
                *(uint4*)(smem + 2304 + c * 144 + uo * 16) = dv;
            }
        }
        __syncthreads();
        {
            const int arow = l & 15;
            const int ull = l >> 4;
#pragma unroll
            for (int kf = 0; kf < 2; ++kf) {
                short8 aF = *(const short8*)(smem + arow * 144 + kf * 64 + ull * 16);
                short8 bF0 = *(const short8*)(smem + 2304 + (w * 32 + arow) * 144 + kf * 64 + ull * 16);
                short8 bF1 = *(const short8*)(smem + 2304 + (w * 32 + 16 + arow) * 144 + kf * 64 + ull * 16);
                acc0 = __builtin_amdgcn_mfma_f32_16x16x32_bf16(aF, bF0, acc0, 0, 0, 0);
                acc1 = __builtin_amdgcn_mfma_f32_16x16x32_bf16(aF, bF1, acc1, 0, 0, 0);
            }
        }
    }
    __syncthreads();
    {
        float* Hs = (float*)smem;
        const int col0 = w * 32 + (l & 15);
        const int rbase = (l >> 4) * 4;
#pragma unroll
        for (int reg = 0; reg < 4; ++reg) {
            Hs[(rbase + reg) * 132 + col0] = tanhf(acc0[reg] + b1[col0]);
            Hs[(rbase + reg) * 132 + col0 + 16] = tanhf(acc1[reg] + b1[col0 + 16]);
        }
    }
    __syncthreads();
    {
        const float* Hs = (const float*)smem;
        const int r = t >> 4;
        const int g = t & 15;
        const int u = u0 + r;
        const unsigned sdw2 = SD[u];
        unsigned vocab = 0;
        if (sdw2 & 1023u)
            vocab = Gb[((sdw2 >> 19) << 9) + ((sdw2 >> 10) & 511u)] >> 9;
        const float4* wrow = (const float4*)(enc + (size_t)vocab * (DMID * DOUT));
        float ax = 0.f, ay = 0.f, az = 0.f, aw = 0.f;
#pragma unroll
        for (int jj = 0; jj < 8; ++jj) {
            int j = jj * 16 + g;
            float4 w4 = wrow[j];
            float hv = Hs[r * 132 + j];
            ax += hv * w4.x; ay += hv * w4.y; az += hv * w4.z; aw += hv * w4.w;
        }
#pragma unroll
        for (int off = 1; off < 16; off <<= 1) {
            ax += __shfl_xor(ax, off);
            ay += __shfl_xor(ay, off);
            az += __shfl_xor(az, off);
            aw += __shfl_xor(aw, off);
        }
        if (g == 0) {
            float4 o;
            o.x = 1.f / (1.f + expf(-ax));
            o.y = 1.f / (1.f + expf(-ay));
            o.z = 1.f / (1.f + expf(-az));
            o.w = 1.f / (1.f + expf(-aw));
            *(float4*)(out_enc + (size_t)u * 4) = o;
        }
    }
}

// ===========================================================================
// FALLBACK (proven R6): single-block LDS sort + transpose + RS-based fused.
// ===========================================================================
#define SORT_SMEM (65536 + 65536 + 4096 + 64)

__global__ __launch_bounds__(1024) void sort_transpose_kernel(
    const int* __restrict__ vocab_ids,
    const float* __restrict__ W1,
    unsigned int* __restrict__ G,
    unsigned short* __restrict__ RS,
    unsigned short* __restrict__ WtG,
    float* __restrict__ out_ids) {
    const int t = threadIdx.x;
    if (blockIdx.x != 0) {
        int idx = (blockIdx.x - 1) * 1024 + t;
        if (idx < DMID * DIN) {
            int c = idx / DIN;
            int k = idx - c * DIN;
            WtG[idx] = (unsigned short)f2bf(W1[k * DMID + c]);
        }
        return;
    }
    extern __shared__ char smem[];
    unsigned* Gs     = (unsigned*)smem;
    unsigned* histDM = (unsigned*)(smem + 65536);
    unsigned* sums   = (unsigned*)(smem + 131072);
    unsigned* totalU = (unsigned*)(smem + 135168);
    for (int e = t; e < NELEM; e += 1024)
        Gs[e] = ((unsigned)vocab_ids[e] << 14) | (unsigned)e;
    __syncthreads();
    for (int pass = 0; pass < 6; ++pass) {
        const int shift = 9 + pass * 4;
        unsigned v[16];
#pragma unroll
        for (int i = 0; i < 16; ++i) v[i] = Gs[t * 16 + i];
#pragma unroll
        for (int d = 0; d < 16; ++d) histDM[d * 1024 + t] = 0;
#pragma unroll
        for (int i = 0; i < 16; ++i) histDM[((v[i] >> shift) & 15u) * 1024 + t] += 1;
        __syncthreads();
        unsigned lex[16]; unsigned run = 0;
#pragma unroll
        for (int i = 0; i < 16; ++i) { unsigned x = histDM[t * 16 + i]; lex[i] = run; run += x; }
        sums[t] = run;
        __syncthreads();
        if (t < 64) {
            unsigned s[16]; unsigned tot = 0;
#pragma unroll
            for (int i = 0; i < 16; ++i) { unsigned x = sums[t * 16 + i]; s[i] = tot; tot += x; }
            unsigned incv = tot;
#pragma unroll
            for (int off = 1; off < 64; off <<= 1) {
                unsigned y = __shfl_up(incv, off);
                if (t >= off) incv += y;
            }
            unsigned excl = incv - tot;
#pragma unroll
            for (int i = 0; i < 16; ++i) sums[t * 16 + i] = excl + s[i];
        }
        __syncthreads();
#pragma unroll
        for (int i = 0; i < 16; ++i) histDM[t * 16 + i] = sums[t] + lex[i];
        __syncthreads();
        unsigned mycnt[16];
#pragma unroll
        for (int d = 0; d < 16; ++d) mycnt[d] = histDM[d * 1024 + t];
#pragma unroll
        for (int i = 0; i < 16; ++i) {
            unsigned d = (v[i] >> shift) & 15u;
            Gs[mycnt[d]++] = v[i];
        }
        __syncthreads();
    }
    unsigned v[16];
#pragma unroll
    for (int i = 0; i < 16; ++i) v[i] = Gs[t * 16 + i];
    unsigned pk = (t == 0) ? 0xFFFFFFFFu : (Gs[t * 16 - 1] >> 9);
    unsigned fm = 0;
#pragma unroll
    for (int i = 0; i < 16; ++i) {
        unsigned key = v[i] >> 9;
        if (key != pk) fm |= (1u << i);
        pk = key;
    }
    sums[t] = (unsigned)__popc(fm);
    __syncthreads();
    if (t < 64) {
        unsigned s[16]; unsigned tot = 0;
#pragma unroll
        for (int i = 0; i < 16; ++i) { unsigned x = sums[t * 16 + i]; s[i] = tot; tot += x; }
        unsigned incv = tot;
#pragma unroll
        for (int off = 1; off < 64; off <<= 1) {
            unsigned y = __shfl_up(incv, off);
            if (t >= off) incv += y;
        }
        unsigned excl = incv - tot;
#pragma unroll
        for (int i = 0; i < 16; ++i) sums[t * 16 + i] = excl + s[i];
        if (t == 63) *totalU = incv;
    }
    __syncthreads();
    unsigned r = sums[t];
#pragma unroll
    for (int i = 0; i < 16; ++i) {
        if (fm & (1u << i)) {
            RS[r] = (unsigned short)(t * 16 + i);
            out_ids[2 * r + 0] = (float)(v[i] >> 14);
            out_ids[2 * r + 1] = (float)((v[i] >> 9) & 31u);
            ++r;
        }
    }
    const unsigned U = *totalU;
    for (int u = t; u < NELEM; u += 1024) {
        if ((unsigned)u >= U) {
            RS[u] = (unsigned short)NELEM;
            out_ids[2 * u + 0] = 0.0f;
            out_ids[2 * u + 1] = 0.0f;
        }
        G[u] = Gs[u];
    }
    if (t == 0) RS[NELEM] = (unsigned short)NELEM;
}

__global__ __launch_bounds__(256) void fused_kernel_rs(
    const unsigned* __restrict__ G,
    const unsigned short* __restrict__ RS,
    const unsigned short* __restrict__ WtG,
    const float* __restrict__ emb,
    const float* __restrict__ b1,
    const float* __restrict__ enc,
    float* __restrict__ out_enc) {
    __shared__ char smem[20736];
    const int t = threadIdx.x;
    const int u0 = blockIdx.x * FBM;
    const int l = t & 63;
    const int w = t >> 6;
    const int ar = t >> 4;
    const int ak4 = t & 15;
    const int rs_a = (int)RS[u0 + ar];
    const int re_a = (int)RS[u0 + ar + 1];
    f32x4 acc0 = {0.f, 0.f, 0.f, 0.f};
    f32x4 acc1 = {0.f, 0.f, 0.f, 0.f};
    for (int kk = 0; kk < DIN; kk += 64) {
        __syncthreads();
        {
            float s0 = 0.f, s1 = 0.f, s2 = 0.f, s3 = 0.f;
            const float* base = emb + (size_t)(kk + ak4 * 4);
            for (int p = rs_a; p < re_a; ++p) {
                unsigned idx = G[p] & 16383u;
                const float4 e4 = *(const float4*)(base + (size_t)idx * DIN);
                s0 += e4.x; s1 += e4.y; s2 += e4.z; s3 += e4.w;
            }
            uint2 packed;
            packed.x = f2bf(s0) | (f2bf(s1) << 16);
            packed.y = f2bf(s2) | (f2bf(s3) << 16);
            *(uint2*)(smem + ar * 144 + ak4 * 8) = packed;
        }
        {
#pragma unroll
            for (int i = 0; i < 4; ++i) {
                int q = t + i * 256;
                int c = q >> 3;
                int uo = q & 7;
                uint4 dv = *(const uint4*)(WtG + (size_t)c * DIN + kk + uo * 8);
                *(uint4*)(smem + 2304 + c * 144 + uo * 16) = dv;
            }
        }
        __syncthreads();
        {
            const int arow = l & 15;
            const int ull = l >> 4;
#pragma unroll
            for (int kf = 0; kf < 2; ++kf) {
                short8 aF = *(const short8*)(smem + arow * 144 + kf * 64 + ull * 16);
                short8 bF0 = *(const short8*)(smem + 2304 + (w * 32 + arow) * 144 + kf * 64 + ull * 16);
                short8 bF1 = *(const short8*)(smem + 2304 + (w * 32 + 16 + arow) * 144 + kf * 64 + ull * 16);
                acc0 = __builtin_amdgcn_mfma_f32_16x16x32_bf16(aF, bF0, acc0, 0, 0, 0);
                acc1 = __builtin_amdgcn_mfma_f32_16x16x32_bf16(aF, bF1, acc1, 0, 0, 0);
            }
        }
    }
    __syncthreads();
    {
        float* Hs = (float*)smem;
        const int col0 = w * 32 + (l & 15);
        const int rbase = (l >> 4) * 4;
#pragma unroll
        for (int reg = 0; reg < 4; ++reg) {
            Hs[(rbase + reg) * 132 + col0] = tanhf(acc0[reg] + b1[col0]);
            Hs[(rbase + reg) * 132 + col0 + 16] = tanhf(acc1[reg] + b1[col0 + 16]);
        }
    }
    __syncthreads();
    {
        const float* Hs = (const float*)smem;
        const int r = t >> 4;
        const int g = t & 15;
        const int u = u0 + r;
        const int rs = (int)RS[u];
        const int re = (int)RS[u + 1];
        unsigned vocab = (rs < re) ? (G[rs] >> 14) : 0u;
        const float4* wrow = (const float4*)(enc + (size_t)vocab * (DMID * DOUT));
        float ax = 0.f, ay = 0.f, az = 0.f, aw = 0.f;
#pragma unroll
        for (int jj = 0; jj < 8; ++jj) {
            int j = jj * 16 + g;
            float4 w4 = wrow[j];
            float hv = Hs[r * 132 + j];
            ax += hv * w4.x; ay += hv * w4.y; az += hv * w4.z; aw += hv * w4.w;
        }
#pragma unroll
        for (int off = 1; off < 16; off <<= 1) {
            ax += __shfl_xor(ax, off);
            ay += __shfl_xor(ay, off);
            az += __shfl_xor(az, off);
            aw += __shfl_xor(aw, off);
        }
        if (g == 0) {
            float4 o;
            o.x = 1.f / (1.f + expf(-ax));
            o.y = 1.f / (1.f + expf(-ay));
            o.z = 1.f / (1.f + expf(-az));
            o.w = 1.f / (1.f + expf(-aw));
            *(float4*)(out_enc + (size_t)u * 4) = o;
        }
    }
}

// ---------------------------------------------------------------------------
extern "C" void kernel_launch(void* const* d_in, const int* in_sizes, int n_in,
                              void* d_out, int out_size, void* d_ws, size_t ws_size,
                              hipStream_t stream) {
    const int*   vocab_ids = (const int*)d_in[0];
    const float* emb       = (const float*)d_in[1];
    const float* W1        = (const float*)d_in[2];
    const float* b1        = (const float*)d_in[3];
    const float* enc       = (const float*)d_in[4];
    float* out = (float*)d_out;
    float* out_ids = out;
    float* out_enc = out + NELEM * 2;
    char* ws = (char*)d_ws;

    if (ws_size >= FAST7_WS) {
        unsigned*           Gb    = (unsigned*)(ws + 0);
        unsigned*           SD    = (unsigned*)(ws + 65536);
        unsigned short*     WtG   = (unsigned short*)(ws + 131072);
        unsigned long long* stage = (unsigned long long*)(ws + 327680);
        unsigned*           LCnt  = (unsigned*)(ws + 458752);
        unsigned*           RB    = (unsigned*)(ws + 458880);
        unsigned*           CS    = (unsigned*)(ws + 983168);
        unsigned*           bar   = (unsigned*)(ws + 999552);

        (void)hipMemsetAsync(bar, 0, 4, stream);
        merged_kernel<<<64, 256, 0, stream>>>(vocab_ids, W1, Gb, SD, WtG,
                                              stage, LCnt, RB, CS, bar, out_ids);
        fused_kernel<<<NELEM / FBM, 256, 0, stream>>>(Gb, SD, WtG, emb, b1, enc, out_enc);
    } else {
        unsigned int*   G   = (unsigned int*)(ws);
        unsigned short* RS  = (unsigned short*)(ws + 65536);
        unsigned short* WtG = (unsigned short*)(ws + 98432);

        (void)hipFuncSetAttribute((const void*)sort_transpose_kernel,
                                  hipFuncAttributeMaxDynamicSharedMemorySize, SORT_SMEM);
        sort_transpose_kernel<<<1 + 96, 1024, SORT_SMEM, stream>>>(
            vocab_ids, W1, G, RS, WtG, out_ids);
        fused_kernel_rs<<<NELEM / FBM, 256, 0, stream>>>(G, RS, WtG, emb, b1, enc, out_enc);
    }
}